// Round 5
// baseline (150.133 us; speedup 1.0000x reference)
//
#include <hip/hip_runtime.h>
#include <hip/hip_cooperative_groups.h>
#include <hip/hip_bf16.h>

#define C_DIM 64
#define N_TOK 4608
#define NBLK  72       // blocks per batch: proj tile = attn m-block = 64 tokens
#define B_SZ  2
#define NSEG  8        // n-segments == waves per attn block
#define SEGLEN (N_TOK / NSEG)   // 576
#define NT64  (SEGLEN / 64)     // 9 n-tiles of 64 tokens per wave
#define KTILES 288     // N_TOK/16 swizzled 16-row K/Q tiles per batch
#define VTILES 72      // N_TOK/64 swizzled 64-token V tiles per batch
#define OSTR  68       // o_lds padded stride (floats)

typedef __bf16 bf16x8 __attribute__((ext_vector_type(8)));
typedef float  f32x4  __attribute__((ext_vector_type(4)));

// ---------------------------------------------------------------------------
// Round 16: single fused cooperative kernel. Evidence synthesis (R12/R13/R15
// nulls + R14 sublinear amplification: +254us GPU work -> +213.7us dur):
// dur = harness_serial(~68us: fill + restore dispatch train) + chain, with
// attn ~14.5us warm all along -- the per-kernel optimizations were sub-noise.
// Remaining controllable: the chain's fixed parts. This round removes the
// norm kernel + 2 launch gaps and tightens proj by fusing proj -> grid.sync
// -> attn into one cooperative launch (144 blocks x 512). Proj: waves 0-3
// compute Q; waves 4-7 compute K and V (identical formulas, wv = wave-4).
// Attn: R11's verified structure verbatim, in-kernel normalize. LDS
// time-shared (proj 55.3KB / attn 36.9KB). Layouts byte-identical to R11.
// ---------------------------------------------------------------------------

namespace cg = cooperative_groups;

__device__ __forceinline__ void gemm_tile(
    const __hip_bfloat16* wmat, const bf16x8 bin[2], const float* bias,
    int col, int quad, f32x4 acc[4])
{
    #pragma unroll
    for (int ot = 0; ot < 4; ot++) {
        f32x4 a = (f32x4){0.f, 0.f, 0.f, 0.f};
        #pragma unroll
        for (int kh = 0; kh < 2; kh++) {
            bf16x8 wf = *(const bf16x8*)(wmat + (ot * 16 + col) * 72 +
                                         kh * 32 + quad * 8);
            a = __builtin_amdgcn_mfma_f32_16x16x32_bf16(wf, bin[kh], a, 0, 0, 0);
        }
        float4 b4 = *(const float4*)(bias + ot * 16 + quad * 4);
        a[0] += b4.x; a[1] += b4.y; a[2] += b4.z; a[3] += b4.w;
        acc[ot] = a;
    }
}

__global__ __launch_bounds__(512) void fused_kernel(
    const float* __restrict__ x,  const float* __restrict__ h,
    const float* __restrict__ Wq, const float* __restrict__ bq,
    const float* __restrict__ Wk, const float* __restrict__ bk,
    const float* __restrict__ Wv, const float* __restrict__ bv,
    __hip_bfloat16* __restrict__ qS, __hip_bfloat16* __restrict__ kS,
    __hip_bfloat16* __restrict__ vS, float* __restrict__ out)
{
    // time-shared LDS: proj {wl 27648B | xt 9216 | ht 9216 | vl 9216} = 55296B
    //                  attn {o_lds 34816B | lstat 2048B}              = 36864B
    __shared__ __align__(16) char smraw[55296];
    __hip_bfloat16* wl = (__hip_bfloat16*)smraw;
    __hip_bfloat16* xt = (__hip_bfloat16*)(smraw + 27648);
    __hip_bfloat16* ht = (__hip_bfloat16*)(smraw + 36864);
    __hip_bfloat16* vl = (__hip_bfloat16*)(smraw + 46080);
    float* o_lds = (float*)smraw;                  // [NSEG*16][OSTR]
    float* lstat = (float*)(smraw + 34816);        // [NSEG][64] flattened

    const int b   = blockIdx.x / NBLK;
    const int nb  = blockIdx.x % NBLK;     // proj 64-token tile / attn m-block
    const int t   = threadIdx.x;
    const int n0b = nb * 64;

    // ================= Phase 1: projections (this block's 64 tokens) =======
    #pragma unroll
    for (int mat = 0; mat < 3; mat++) {
        const float* W = (mat == 0) ? Wq : ((mat == 1) ? Wk : Wv);
        __hip_bfloat16* wd = wl + mat * (64 * 72);
        #pragma unroll
        for (int i = 0; i < 2; i++) {
            const int ch = i * 512 + t;
            const int o = ch >> 4, c0 = (ch & 15) * 4;
            float4 w4 = *(const float4*)(W + ch * 4);
            union { __hip_bfloat16 e[4]; uint2 v; } pk;
            pk.e[0] = __float2bfloat16(w4.x); pk.e[1] = __float2bfloat16(w4.y);
            pk.e[2] = __float2bfloat16(w4.z); pk.e[3] = __float2bfloat16(w4.w);
            *(uint2*)(wd + o * 72 + c0) = pk.v;
        }
    }
    #pragma unroll
    for (int i = 0; i < 2; i++) {
        const int ch = i * 512 + t;
        const int c = ch >> 4, n4 = (ch & 15) * 4;
        float4 x4 = *(const float4*)(x + (size_t)(b * C_DIM + c) * N_TOK + n0b + n4);
        float4 h4 = *(const float4*)(h + (size_t)(b * C_DIM + c) * N_TOK + n0b + n4);
        xt[(n4 + 0) * 72 + c] = __float2bfloat16(x4.x);
        xt[(n4 + 1) * 72 + c] = __float2bfloat16(x4.y);
        xt[(n4 + 2) * 72 + c] = __float2bfloat16(x4.z);
        xt[(n4 + 3) * 72 + c] = __float2bfloat16(x4.w);
        ht[(n4 + 0) * 72 + c] = __float2bfloat16(h4.x);
        ht[(n4 + 1) * 72 + c] = __float2bfloat16(h4.y);
        ht[(n4 + 2) * 72 + c] = __float2bfloat16(h4.z);
        ht[(n4 + 3) * 72 + c] = __float2bfloat16(h4.w);
    }
    __syncthreads();

    const int wave = t >> 6, lane = t & 63;
    const int col = lane & 15, quad = lane >> 4;

    if (wave < 4) {
        // ---- Q path (waves 0-3, identical to R11 proj wave mapping) ----
        bf16x8 xb[2];
        #pragma unroll
        for (int kh = 0; kh < 2; kh++)
            xb[kh] = *(const bf16x8*)(xt + (wave * 16 + col) * 72 +
                                      kh * 32 + quad * 8);
        f32x4 acc[4];
        gemm_tile(wl, xb, bq, col, quad, acc);
        const size_t tile16 = (size_t)b * KTILES + (n0b >> 4) + wave;
        const float SC = 0.125f * 1.44269504088896f;
        #pragma unroll
        for (int ot = 0; ot < 4; ot++) {
            union { __hip_bfloat16 e[4]; uint2 v; } pk;
            #pragma unroll
            for (int r = 0; r < 4; r++) pk.e[r] = __float2bfloat16(acc[ot][r] * SC);
            *(uint2*)(qS + (tile16 << 10) + (ot >> 1) * 512 +
                      ((ot * 2 + (quad >> 1)) & 3) * 128 + col * 8 +
                      (quad & 1) * 4) = pk.v;
        }
    } else {
        // ---- K + V path (waves 4-7; wv = wave-4 replicates R11 formulas) --
        const int wv = wave - 4;
        bf16x8 hb[2];
        #pragma unroll
        for (int kh = 0; kh < 2; kh++)
            hb[kh] = *(const bf16x8*)(ht + (wv * 16 + col) * 72 +
                                      kh * 32 + quad * 8);
        f32x4 acc[4];
        gemm_tile(wl + 1 * (64 * 72), hb, bk, col, quad, acc);
        {
            const int t_l = (wv >> 1) * 2 + ((col >> 2) & 1);
            const int row = ((wv * 2 + (col >> 3)) & 3) * 4 + (col & 3);
            const size_t tile16 = (size_t)b * KTILES + (n0b >> 4) + t_l;
            #pragma unroll
            for (int ot = 0; ot < 4; ot++) {
                union { __hip_bfloat16 e[4]; uint2 v; } pk;
                #pragma unroll
                for (int r = 0; r < 4; r++) pk.e[r] = __float2bfloat16(acc[ot][r]);
                *(uint2*)(kS + (tile16 << 10) + (ot >> 1) * 512 +
                          ((ot * 2 + (quad >> 1)) & 3) * 128 + row * 8 +
                          (quad & 1) * 4) = pk.v;
            }
        }
        gemm_tile(wl + 2 * (64 * 72), hb, bv, col, quad, acc);
        #pragma unroll
        for (int ot = 0; ot < 4; ot++)
            #pragma unroll
            for (int r = 0; r < 4; r++)
                vl[(ot * 16 + quad * 4 + r) * 72 + wv * 16 + col] =
                    __float2bfloat16(acc[ot][r]);
    }
    __syncthreads();
    {
        // vS store: 512 threads cover the 8KB payload in one pass
        const size_t vbase = ((size_t)(b * VTILES) + (n0b >> 6)) << 12;
        const int cc = t >> 7, hf = (t >> 6) & 1;
        const int qd = (t >> 4) & 3, c2 = t & 15;
        *(uint4*)(vS + vbase + (size_t)t * 8) =
            *(const uint4*)(vl + (cc * 16 + c2) * 72 + hf * 32 + qd * 8);
    }

    // ================= grid-wide barrier: all q/k/v tiles visible ==========
    __threadfence();
    cg::this_grid().sync();

    // ================= Phase 2: flash attention (R11 structure) ============
    const int m0 = nb * 64;

    const __hip_bfloat16* qp =
        qS + (((size_t)b * KTILES + (m0 >> 4)) << 10) + lane * 8;
    bf16x8 qa[4][2];
    #pragma unroll
    for (int ms = 0; ms < 4; ms++) {
        qa[ms][0] = *(const bf16x8*)(qp + ms * 1024);
        qa[ms][1] = *(const bf16x8*)(qp + ms * 1024 + 512);
    }

    f32x4 accO[4][4];
    #pragma unroll
    for (int ms = 0; ms < 4; ms++)
        #pragma unroll
        for (int cc = 0; cc < 4; cc++)
            accO[ms][cc] = (f32x4){0.f, 0.f, 0.f, 0.f};
    float rsum[4] = {0.f, 0.f, 0.f, 0.f};

    const int nbeg = wave * SEGLEN;

    #pragma unroll 1
    for (int tt = 0; tt < NT64; tt++) {
        const int n0 = nbeg + tt * 64;
        const __hip_bfloat16* kt =
            kS + (((size_t)b * KTILES + (n0 >> 4)) << 10) + lane * 8;
        bf16x8 ka[8];
        #pragma unroll
        for (int j = 0; j < 4; j++) {
            ka[2 * j]     = *(const bf16x8*)(kt + (j << 10));
            ka[2 * j + 1] = *(const bf16x8*)(kt + (j << 10) + 512);
        }
        const __hip_bfloat16* vt =
            vS + ((((size_t)b * VTILES) + (n0 >> 6)) << 12) + lane * 8;
        bf16x8 va[8];
        #pragma unroll
        for (int cc = 0; cc < 4; cc++) {
            va[2 * cc]     = *(const bf16x8*)(vt + cc * 1024);
            va[2 * cc + 1] = *(const bf16x8*)(vt + cc * 1024 + 512);
        }

        #pragma unroll
        for (int ms = 0; ms < 4; ms++) {
            f32x4 s[4];
            #pragma unroll
            for (int j = 0; j < 4; j++) {
                s[j] = __builtin_amdgcn_mfma_f32_16x16x32_bf16(
                           ka[2 * j], qa[ms][0],
                           (f32x4){0.f, 0.f, 0.f, 0.f}, 0, 0, 0);
                s[j] = __builtin_amdgcn_mfma_f32_16x16x32_bf16(
                           ka[2 * j + 1], qa[ms][1], s[j], 0, 0, 0);
            }
            union { __hip_bfloat16 e[8]; bf16x8 v; } p0, p1;
            float ps = 0.f;
            #pragma unroll
            for (int j = 0; j < 2; j++)
                #pragma unroll
                for (int r = 0; r < 4; r++) {
                    float e0 = __builtin_amdgcn_exp2f(s[j][r]);
                    float e1 = __builtin_amdgcn_exp2f(s[2 + j][r]);
                    ps += e0 + e1;
                    p0.e[j * 4 + r] = __float2bfloat16(e0);
                    p1.e[j * 4 + r] = __float2bfloat16(e1);
                }
            rsum[ms] += ps;
            #pragma unroll
            for (int cc = 0; cc < 4; cc++) {
                accO[ms][cc] = __builtin_amdgcn_mfma_f32_16x16x32_bf16(
                                   va[2 * cc], p0.v, accO[ms][cc], 0, 0, 0);
                accO[ms][cc] = __builtin_amdgcn_mfma_f32_16x16x32_bf16(
                                   va[2 * cc + 1], p1.v, accO[ms][cc], 0, 0, 0);
            }
        }
    }

    // ---- finalize per-wave stats ----
    #pragma unroll
    for (int ms = 0; ms < 4; ms++) {
        rsum[ms] += __shfl_xor(rsum[ms], 16);
        rsum[ms] += __shfl_xor(rsum[ms], 32);
    }
    __syncthreads();   // proj-phase LDS (vl) fully consumed; alias to attn use
    if (quad == 0) {
        #pragma unroll
        for (int ms = 0; ms < 4; ms++) lstat[wave * 64 + ms * 16 + col] = rsum[ms];
    }

    // ---- four-phase combine over 8 segments (o_lds reused per phase) ----
    #pragma unroll
    for (int phase = 0; phase < 4; phase++) {
        #pragma unroll
        for (int cc = 0; cc < 4; cc++)
            *(f32x4*)(o_lds + (wave * 16 + col) * OSTR + cc * 16 + quad * 4) =
                accO[phase][cc];
        __syncthreads();
        if (threadIdx.x < 256) {
            const int m  = threadIdx.x & 15;
            const int cq = threadIdx.x >> 4;
            const int mi = phase * 16 + m;
            float lsum = 0.f;
            f32x4 oacc = (f32x4){0.f, 0.f, 0.f, 0.f};
            #pragma unroll
            for (int sgm = 0; sgm < NSEG; sgm++) {
                lsum += lstat[sgm * 64 + mi];
                oacc += *(const f32x4*)(o_lds + (sgm * 16 + m) * OSTR + cq * 4);
            }
            const float inv = 1.0f / lsum;
            #pragma unroll
            for (int r = 0; r < 4; r++) {
                const int c = cq * 4 + r;
                out[(size_t)(b * C_DIM + c) * N_TOK + m0 + phase * 16 + m] =
                    oacc[r] * inv;
            }
        }
        __syncthreads();
    }
}

extern "C" void kernel_launch(void* const* d_in, const int* in_sizes, int n_in,
                              void* d_out, int out_size, void* d_ws, size_t ws_size,
                              hipStream_t stream) {
    const float* x  = (const float*)d_in[0];
    const float* h  = (const float*)d_in[1];
    const float* Wq = (const float*)d_in[2];
    const float* bq = (const float*)d_in[3];
    const float* Wk = (const float*)d_in[4];
    const float* bk = (const float*)d_in[5];
    const float* Wv = (const float*)d_in[6];
    const float* bv = (const float*)d_in[7];
    float* out = (float*)d_out;

    const size_t elems = (size_t)B_SZ * N_TOK * C_DIM;   // 589824
    __hip_bfloat16* qS = (__hip_bfloat16*)d_ws;
    __hip_bfloat16* kS = qS + elems;
    __hip_bfloat16* vS = kS + elems;

    void* args[] = { (void*)&x, (void*)&h, (void*)&Wq, (void*)&bq,
                     (void*)&Wk, (void*)&bk, (void*)&Wv, (void*)&bv,
                     (void*)&qS, (void*)&kS, (void*)&vS, (void*)&out };
    hipLaunchCooperativeKernel((void*)fused_kernel,
                               dim3(B_SZ * NBLK), dim3(512), args, 0, stream);
}

// Round 6
// 143.567 us; speedup vs baseline: 1.0457x; 1.0457x over previous
//
#include <hip/hip_runtime.h>
#include <hip/hip_bf16.h>

#define C_DIM 64
#define N_TOK 4608
#define NBLK  72       // proj blocks per batch (64 tokens each)
#define B_SZ  2
#define M128BLKS 36    // attn m-blocks per batch (128 m-tokens each)
#define NSPLIT 3       // n-splits across blocks (1536 tokens each)
#define NSEG  4        // n-segments per m-group inside a block (4 waves)
#define SEGLEN 384     // 1536 / NSEG tokens per wave
#define NT    6        // 384/64 tiles per wave
#define KTILES 288     // N_TOK/16 swizzled 16-row K/Q tiles per batch
#define VTILES 72      // N_TOK/64 swizzled 64-token V tiles per batch
#define OSTR  68       // o_lds padded stride (floats)
#define PSTR  ((size_t)B_SZ * C_DIM * N_TOK)   // 589824 floats per P split
#define LSTR  ((size_t)B_SZ * N_TOK)           // 9216 floats per L split

typedef __bf16 bf16x8 __attribute__((ext_vector_type(8)));
typedef float  f32x4  __attribute__((ext_vector_type(4)));

// ---------------------------------------------------------------------------
// Round 17: revert R16 (fused cooperative = 57us kernel, all pipes idle --
// grid.sync + fence recreated chip-wide cold reads; regression). Back to R15
// (best, 92.5us) + fold norm_kernel into attn via last-block-done ticket:
// proj zero-inits 72 counters; each attn block release-fences, atomicAdds
// its (b,mblk) counter; the 3rd arriver acquire-fences and runs the old
// norm body for its m-block (identical f32x4 sum order -> identical output).
// Saves the norm dispatch + launch gap; finisher tails overlap compute.
// ---------------------------------------------------------------------------

__device__ __forceinline__ void gemm_tile(
    const __hip_bfloat16* wmat, const bf16x8 bin[2], const float* bias,
    int col, int quad, f32x4 acc[4])
{
    #pragma unroll
    for (int ot = 0; ot < 4; ot++) {
        f32x4 a = (f32x4){0.f, 0.f, 0.f, 0.f};
        #pragma unroll
        for (int kh = 0; kh < 2; kh++) {
            bf16x8 wf = *(const bf16x8*)(wmat + (ot * 16 + col) * 72 +
                                         kh * 32 + quad * 8);
            a = __builtin_amdgcn_mfma_f32_16x16x32_bf16(wf, bin[kh], a, 0, 0, 0);
        }
        float4 b4 = *(const float4*)(bias + ot * 16 + quad * 4);
        a[0] += b4.x; a[1] += b4.y; a[2] += b4.z; a[3] += b4.w;
        acc[ot] = a;
    }
}

__global__ __launch_bounds__(256) void proj_kernel(
    const float* __restrict__ x,  const float* __restrict__ h,
    const float* __restrict__ Wq, const float* __restrict__ bq,
    const float* __restrict__ Wk, const float* __restrict__ bk,
    const float* __restrict__ Wv, const float* __restrict__ bv,
    __hip_bfloat16* __restrict__ qS, __hip_bfloat16* __restrict__ kS,
    __hip_bfloat16* __restrict__ vS, int* __restrict__ cnt)
{
    __shared__ __hip_bfloat16 wl[3 * 64 * 72];
    __shared__ __hip_bfloat16 xt[64 * 72];
    __shared__ __hip_bfloat16 ht[64 * 72];
    __shared__ __hip_bfloat16 vl[64 * 72];

    const int b  = blockIdx.x / NBLK;
    const int nb = blockIdx.x % NBLK;
    const int n0 = nb * 64;
    const int t  = threadIdx.x;

    // zero the attn completion counters (workspace is poisoned each iter);
    // kernel boundary orders this before attn_kernel's atomics.
    if (nb < M128BLKS && t == 0) cnt[b * M128BLKS + nb] = 0;

    #pragma unroll
    for (int mat = 0; mat < 3; mat++) {
        const float* W = (mat == 0) ? Wq : ((mat == 1) ? Wk : Wv);
        __hip_bfloat16* wd = wl + mat * (64 * 72);
        #pragma unroll
        for (int i = 0; i < 4; i++) {
            const int ch = i * 256 + t;
            const int o = ch >> 4, c0 = (ch & 15) * 4;
            float4 w4 = *(const float4*)(W + ch * 4);
            union { __hip_bfloat16 e[4]; uint2 v; } pk;
            pk.e[0] = __float2bfloat16(w4.x); pk.e[1] = __float2bfloat16(w4.y);
            pk.e[2] = __float2bfloat16(w4.z); pk.e[3] = __float2bfloat16(w4.w);
            *(uint2*)(wd + o * 72 + c0) = pk.v;
        }
    }
    #pragma unroll
    for (int i = 0; i < 4; i++) {
        const int ch = i * 256 + t;
        const int c = ch >> 4, n4 = (ch & 15) * 4;
        float4 x4 = *(const float4*)(x + (size_t)(b * C_DIM + c) * N_TOK + n0 + n4);
        float4 h4 = *(const float4*)(h + (size_t)(b * C_DIM + c) * N_TOK + n0 + n4);
        xt[(n4 + 0) * 72 + c] = __float2bfloat16(x4.x);
        xt[(n4 + 1) * 72 + c] = __float2bfloat16(x4.y);
        xt[(n4 + 2) * 72 + c] = __float2bfloat16(x4.z);
        xt[(n4 + 3) * 72 + c] = __float2bfloat16(x4.w);
        ht[(n4 + 0) * 72 + c] = __float2bfloat16(h4.x);
        ht[(n4 + 1) * 72 + c] = __float2bfloat16(h4.y);
        ht[(n4 + 2) * 72 + c] = __float2bfloat16(h4.z);
        ht[(n4 + 3) * 72 + c] = __float2bfloat16(h4.w);
    }
    __syncthreads();

    const int wave = t >> 6, lane = t & 63;
    const int col = lane & 15, quad = lane >> 4;

    bf16x8 xb[2], hb[2];
    #pragma unroll
    for (int kh = 0; kh < 2; kh++) {
        xb[kh] = *(const bf16x8*)(xt + (wave * 16 + col) * 72 + kh * 32 + quad * 8);
        hb[kh] = *(const bf16x8*)(ht + (wave * 16 + col) * 72 + kh * 32 + quad * 8);
    }

    f32x4 acc[4];

    gemm_tile(wl + 0 * (64 * 72), xb, bq, col, quad, acc);
    {
        const size_t tile16 = (size_t)b * KTILES + (n0 >> 4) + wave;
        const float SC = 0.125f * 1.44269504088896f;
        #pragma unroll
        for (int ot = 0; ot < 4; ot++) {
            union { __hip_bfloat16 e[4]; uint2 v; } pk;
            #pragma unroll
            for (int r = 0; r < 4; r++) pk.e[r] = __float2bfloat16(acc[ot][r] * SC);
            *(uint2*)(qS + (tile16 << 10) + (ot >> 1) * 512 +
                      ((ot * 2 + (quad >> 1)) & 3) * 128 + col * 8 +
                      (quad & 1) * 4) = pk.v;
        }
    }

    gemm_tile(wl + 1 * (64 * 72), hb, bk, col, quad, acc);
    {
        const int t_l = (wave >> 1) * 2 + ((col >> 2) & 1);
        const int row = ((wave * 2 + (col >> 3)) & 3) * 4 + (col & 3);
        const size_t tile16 = (size_t)b * KTILES + (n0 >> 4) + t_l;
        #pragma unroll
        for (int ot = 0; ot < 4; ot++) {
            union { __hip_bfloat16 e[4]; uint2 v; } pk;
            #pragma unroll
            for (int r = 0; r < 4; r++) pk.e[r] = __float2bfloat16(acc[ot][r]);
            *(uint2*)(kS + (tile16 << 10) + (ot >> 1) * 512 +
                      ((ot * 2 + (quad >> 1)) & 3) * 128 + row * 8 +
                      (quad & 1) * 4) = pk.v;
        }
    }

    gemm_tile(wl + 2 * (64 * 72), hb, bv, col, quad, acc);
    #pragma unroll
    for (int ot = 0; ot < 4; ot++)
        #pragma unroll
        for (int r = 0; r < 4; r++)
            vl[(ot * 16 + quad * 4 + r) * 72 + wave * 16 + col] =
                __float2bfloat16(acc[ot][r]);
    __syncthreads();
    {
        const size_t vbase = ((size_t)(b * VTILES) + (n0 >> 6)) << 12;
        #pragma unroll
        for (int rep = 0; rep < 2; rep++) {
            const int ch = rep * 256 + t;
            const int cc = ch >> 7, hf = (ch >> 6) & 1;
            const int qd = (ch >> 4) & 3, c2 = ch & 15;
            *(uint4*)(vS + vbase + (size_t)ch * 8) =
                *(const uint4*)(vl + (cc * 16 + c2) * 72 + hf * 32 + qd * 8);
        }
    }
}

// ---------------------------------------------------------------------------
// Flash attention partials + in-kernel normalize-on-last-arrival.
// grid = B * 36 * 3 = 216 blocks of 512. Block (b, mblk, ns): rows
// [mblk*128,+128), tokens [ns*1536,+1536). Per-wave loop identical to R15.
// After writing partials: release-fence + atomicAdd; 3rd arriver runs the
// norm body for this m-block (identical sum order to the old norm_kernel).
// ---------------------------------------------------------------------------
__global__ __launch_bounds__(512) void attn_kernel(
    const __hip_bfloat16* __restrict__ qS,
    const __hip_bfloat16* __restrict__ kS,
    const __hip_bfloat16* __restrict__ vS,
    float* __restrict__ Pb, float* __restrict__ Lb,
    int* __restrict__ cnt, float* __restrict__ out)
{
    __shared__ float o_lds[2][NSEG][16][OSTR];   // 34.8 KB
    __shared__ float lstat[2][NSEG][64];         // 2 KB
    __shared__ int fin;

    const int idx  = blockIdx.x;
    const int b    = idx / (M128BLKS * NSPLIT);
    const int rem  = idx % (M128BLKS * NSPLIT);
    const int mblk = rem / NSPLIT;
    const int ns   = rem % NSPLIT;
    const int wave = threadIdx.x >> 6;
    const int lane = threadIdx.x & 63;
    const int col  = lane & 15;
    const int quad = lane >> 4;
    const int mg   = wave >> 2;      // 64-row half
    const int seg  = wave & 3;       // 384-token quarter
    const int m0   = mblk * 128 + mg * 64;

    float* Pns = Pb + (size_t)ns * PSTR;
    float* Lns = Lb + (size_t)ns * LSTR;

    const __hip_bfloat16* qp =
        qS + (((size_t)b * KTILES + (m0 >> 4)) << 10) + lane * 8;
    bf16x8 qa[4][2];
    #pragma unroll
    for (int ms = 0; ms < 4; ms++) {
        qa[ms][0] = *(const bf16x8*)(qp + ms * 1024);
        qa[ms][1] = *(const bf16x8*)(qp + ms * 1024 + 512);
    }

    f32x4 accO[4][4];
    #pragma unroll
    for (int ms = 0; ms < 4; ms++)
        #pragma unroll
        for (int cc = 0; cc < 4; cc++)
            accO[ms][cc] = (f32x4){0.f, 0.f, 0.f, 0.f};
    float rsum[4] = {0.f, 0.f, 0.f, 0.f};

    const int nbeg = ns * (NSEG * SEGLEN) + seg * SEGLEN;

    #pragma unroll 1
    for (int t = 0; t < NT; t++) {
        const int n0 = nbeg + t * 64;
        const __hip_bfloat16* kt =
            kS + (((size_t)b * KTILES + (n0 >> 4)) << 10) + lane * 8;
        bf16x8 ka[8];
        #pragma unroll
        for (int j = 0; j < 4; j++) {
            ka[2 * j]     = *(const bf16x8*)(kt + (j << 10));
            ka[2 * j + 1] = *(const bf16x8*)(kt + (j << 10) + 512);
        }
        const __hip_bfloat16* vt =
            vS + ((((size_t)b * VTILES) + (n0 >> 6)) << 12) + lane * 8;
        bf16x8 va[8];
        #pragma unroll
        for (int cc = 0; cc < 4; cc++) {
            va[2 * cc]     = *(const bf16x8*)(vt + cc * 1024);
            va[2 * cc + 1] = *(const bf16x8*)(vt + cc * 1024 + 512);
        }

        #pragma unroll
        for (int ms = 0; ms < 4; ms++) {
            f32x4 s[4];
            #pragma unroll
            for (int j = 0; j < 4; j++) {
                s[j] = __builtin_amdgcn_mfma_f32_16x16x32_bf16(
                           ka[2 * j], qa[ms][0],
                           (f32x4){0.f, 0.f, 0.f, 0.f}, 0, 0, 0);
                s[j] = __builtin_amdgcn_mfma_f32_16x16x32_bf16(
                           ka[2 * j + 1], qa[ms][1], s[j], 0, 0, 0);
            }
            union { __hip_bfloat16 e[8]; bf16x8 v; } p0, p1;
            float ps = 0.f;
            #pragma unroll
            for (int j = 0; j < 2; j++)
                #pragma unroll
                for (int r = 0; r < 4; r++) {
                    float e0 = __builtin_amdgcn_exp2f(s[j][r]);
                    float e1 = __builtin_amdgcn_exp2f(s[2 + j][r]);
                    ps += e0 + e1;
                    p0.e[j * 4 + r] = __float2bfloat16(e0);
                    p1.e[j * 4 + r] = __float2bfloat16(e1);
                }
            rsum[ms] += ps;
            #pragma unroll
            for (int cc = 0; cc < 4; cc++) {
                accO[ms][cc] = __builtin_amdgcn_mfma_f32_16x16x32_bf16(
                                   va[2 * cc], p0.v, accO[ms][cc], 0, 0, 0);
                accO[ms][cc] = __builtin_amdgcn_mfma_f32_16x16x32_bf16(
                                   va[2 * cc + 1], p1.v, accO[ms][cc], 0, 0, 0);
            }
        }
    }

    // ---- finalize per-wave softmax sums ----
    #pragma unroll
    for (int ms = 0; ms < 4; ms++) {
        rsum[ms] += __shfl_xor(rsum[ms], 16);
        rsum[ms] += __shfl_xor(rsum[ms], 32);
    }
    if (quad == 0) {
        #pragma unroll
        for (int ms = 0; ms < 4; ms++) lstat[mg][seg][ms * 16 + col] = rsum[ms];
    }

    // ---- four-phase combine over 4 segments; write P/L partials ----
    #pragma unroll
    for (int p = 0; p < 4; p++) {
        #pragma unroll
        for (int cc = 0; cc < 4; cc++)
            *(f32x4*)(&o_lds[mg][seg][col][cc * 16 + quad * 4]) = accO[p][cc];
        __syncthreads();
        {
            const int t   = threadIdx.x;
            const int mgR = t >> 8;
            const int c   = (t >> 2) & 63;
            const int mq  = t & 3;
            f32x4 os = (f32x4){0.f, 0.f, 0.f, 0.f};
            f32x4 ls = (f32x4){0.f, 0.f, 0.f, 0.f};
            #pragma unroll
            for (int sgm = 0; sgm < NSEG; sgm++)
                #pragma unroll
                for (int j = 0; j < 4; j++) {
                    os[j] += o_lds[mgR][sgm][mq * 4 + j][c];
                    ls[j] += lstat[mgR][sgm][p * 16 + mq * 4 + j];
                }
            const int mabs = mblk * 128 + mgR * 64 + p * 16 + mq * 4;
            *(f32x4*)(Pns + ((size_t)b * C_DIM + c) * N_TOK + mabs) = os;
            if (c == 0)
                *(f32x4*)(Lns + (size_t)b * N_TOK + mabs) = ls;
        }
        __syncthreads();
    }

    // ---- last-arriver normalization (replaces norm_kernel) ----
    __threadfence();                 // release: partials visible device-wide
    __syncthreads();                 // all threads' fences precede the ticket
    if (threadIdx.x == 0) {
        const int old = atomicAdd(&cnt[b * M128BLKS + mblk], 1);
        fin = (old == NSPLIT - 1);
    }
    __syncthreads();
    if (!fin) return;
    __threadfence();                 // acquire: other splits' partials visible

    const int mbase = mblk * 128;
    #pragma unroll
    for (int i = 0; i < 4; i++) {
        const int v  = i * 512 + (int)threadIdx.x;   // 0..2047
        const int c  = v >> 5;                       // channel 0..63
        const int mq = v & 31;                       // 4-row group within 128
        const size_t off = ((size_t)b * C_DIM + c) * N_TOK + mbase + mq * 4;
        f32x4 o = *(const f32x4*)(Pb + off) +
                  *(const f32x4*)(Pb + PSTR + off) +
                  *(const f32x4*)(Pb + 2 * PSTR + off);
        const size_t loff = (size_t)b * N_TOK + mbase + mq * 4;
        f32x4 l = *(const f32x4*)(Lb + loff) +
                  *(const f32x4*)(Lb + LSTR + loff) +
                  *(const f32x4*)(Lb + 2 * LSTR + loff);
        f32x4 r;
        #pragma unroll
        for (int j = 0; j < 4; j++) r[j] = o[j] / l[j];
        *(f32x4*)(out + off) = r;
    }
}

extern "C" void kernel_launch(void* const* d_in, const int* in_sizes, int n_in,
                              void* d_out, int out_size, void* d_ws, size_t ws_size,
                              hipStream_t stream) {
    const float* x  = (const float*)d_in[0];
    const float* h  = (const float*)d_in[1];
    const float* Wq = (const float*)d_in[2];
    const float* bq = (const float*)d_in[3];
    const float* Wk = (const float*)d_in[4];
    const float* bk = (const float*)d_in[5];
    const float* Wv = (const float*)d_in[6];
    const float* bv = (const float*)d_in[7];
    float* out = (float*)d_out;

    const size_t elems = (size_t)B_SZ * N_TOK * C_DIM;   // 589824
    __hip_bfloat16* qS = (__hip_bfloat16*)d_ws;
    __hip_bfloat16* kS = qS + elems;
    __hip_bfloat16* vS = kS + elems;
    float* Pb = (float*)(vS + elems);                    // 3 x 2.36 MB
    float* Lb = Pb + NSPLIT * elems;                     // 3 x 36.9 KB
    int*   cnt = (int*)(Lb + NSPLIT * (size_t)B_SZ * N_TOK);  // 72 ints

    proj_kernel<<<B_SZ * NBLK, 256, 0, stream>>>(x, h, Wq, bq, Wk, bk, Wv, bv,
                                                 qS, kS, vS, cnt);
    attn_kernel<<<B_SZ * M128BLKS * NSPLIT, 512, 0, stream>>>(qS, kS, vS,
                                                              Pb, Lb, cnt, out);
}

// Round 7
// 92.143 us; speedup vs baseline: 1.6294x; 1.5581x over previous
//
#include <hip/hip_runtime.h>
#include <hip/hip_bf16.h>

#define C_DIM 64
#define N_TOK 4608
#define NBLK  72       // proj blocks per batch (64 tokens each)
#define B_SZ  2
#define M128BLKS 36    // attn m-blocks per batch (128 m-tokens each)
#define NSPLIT 3       // n-splits across blocks (1536 tokens each)
#define NSEG  4        // n-segments per m-group inside a block (4 waves)
#define SEGLEN 384     // 1536 / NSEG tokens per wave
#define NT    6        // 384/64 tiles per wave
#define KTILES 288     // N_TOK/16 swizzled 16-row K/Q tiles per batch
#define VTILES 72      // N_TOK/64 swizzled 64-token V tiles per batch
#define OSTR  68       // o_lds padded stride (floats)

typedef __bf16 bf16x8 __attribute__((ext_vector_type(8)));
typedef float  f32x4  __attribute__((ext_vector_type(4)));

// ---------------------------------------------------------------------------
// Round 18: REVERT to R15 verbatim (best verified: 92.475 us). R17's
// device-scope threadfence + last-arriver ticket cost ~50us (attn 78-83us,
// all pipes idle -- L2 writeback serialization on non-coherent XCD L2s),
// mirroring R16's grid.sync regression. Rule learned: on gfx950, kernel
// launch boundaries are CHEAPER than any device-scope ordering primitive.
// Evidence matrix (R12/R13/R15 null, R16/R17 regress, R14 amplification):
// dur = fill(42us @80% HBM peak, harness-fixed) + restores/launch machinery
// + ~22us chain that is insensitive to +-5us structural perturbation.
// ---------------------------------------------------------------------------

__device__ __forceinline__ void gemm_tile(
    const __hip_bfloat16* wmat, const bf16x8 bin[2], const float* bias,
    int col, int quad, f32x4 acc[4])
{
    #pragma unroll
    for (int ot = 0; ot < 4; ot++) {
        f32x4 a = (f32x4){0.f, 0.f, 0.f, 0.f};
        #pragma unroll
        for (int kh = 0; kh < 2; kh++) {
            bf16x8 wf = *(const bf16x8*)(wmat + (ot * 16 + col) * 72 +
                                         kh * 32 + quad * 8);
            a = __builtin_amdgcn_mfma_f32_16x16x32_bf16(wf, bin[kh], a, 0, 0, 0);
        }
        float4 b4 = *(const float4*)(bias + ot * 16 + quad * 4);
        a[0] += b4.x; a[1] += b4.y; a[2] += b4.z; a[3] += b4.w;
        acc[ot] = a;
    }
}

__global__ __launch_bounds__(256) void proj_kernel(
    const float* __restrict__ x,  const float* __restrict__ h,
    const float* __restrict__ Wq, const float* __restrict__ bq,
    const float* __restrict__ Wk, const float* __restrict__ bk,
    const float* __restrict__ Wv, const float* __restrict__ bv,
    __hip_bfloat16* __restrict__ qS, __hip_bfloat16* __restrict__ kS,
    __hip_bfloat16* __restrict__ vS)
{
    __shared__ __hip_bfloat16 wl[3 * 64 * 72];
    __shared__ __hip_bfloat16 xt[64 * 72];
    __shared__ __hip_bfloat16 ht[64 * 72];
    __shared__ __hip_bfloat16 vl[64 * 72];

    const int b  = blockIdx.x / NBLK;
    const int n0 = (blockIdx.x % NBLK) * 64;
    const int t  = threadIdx.x;

    #pragma unroll
    for (int mat = 0; mat < 3; mat++) {
        const float* W = (mat == 0) ? Wq : ((mat == 1) ? Wk : Wv);
        __hip_bfloat16* wd = wl + mat * (64 * 72);
        #pragma unroll
        for (int i = 0; i < 4; i++) {
            const int ch = i * 256 + t;
            const int o = ch >> 4, c0 = (ch & 15) * 4;
            float4 w4 = *(const float4*)(W + ch * 4);
            union { __hip_bfloat16 e[4]; uint2 v; } pk;
            pk.e[0] = __float2bfloat16(w4.x); pk.e[1] = __float2bfloat16(w4.y);
            pk.e[2] = __float2bfloat16(w4.z); pk.e[3] = __float2bfloat16(w4.w);
            *(uint2*)(wd + o * 72 + c0) = pk.v;
        }
    }
    #pragma unroll
    for (int i = 0; i < 4; i++) {
        const int ch = i * 256 + t;
        const int c = ch >> 4, n4 = (ch & 15) * 4;
        float4 x4 = *(const float4*)(x + (size_t)(b * C_DIM + c) * N_TOK + n0 + n4);
        float4 h4 = *(const float4*)(h + (size_t)(b * C_DIM + c) * N_TOK + n0 + n4);
        xt[(n4 + 0) * 72 + c] = __float2bfloat16(x4.x);
        xt[(n4 + 1) * 72 + c] = __float2bfloat16(x4.y);
        xt[(n4 + 2) * 72 + c] = __float2bfloat16(x4.z);
        xt[(n4 + 3) * 72 + c] = __float2bfloat16(x4.w);
        ht[(n4 + 0) * 72 + c] = __float2bfloat16(h4.x);
        ht[(n4 + 1) * 72 + c] = __float2bfloat16(h4.y);
        ht[(n4 + 2) * 72 + c] = __float2bfloat16(h4.z);
        ht[(n4 + 3) * 72 + c] = __float2bfloat16(h4.w);
    }
    __syncthreads();

    const int wave = t >> 6, lane = t & 63;
    const int col = lane & 15, quad = lane >> 4;

    bf16x8 xb[2], hb[2];
    #pragma unroll
    for (int kh = 0; kh < 2; kh++) {
        xb[kh] = *(const bf16x8*)(xt + (wave * 16 + col) * 72 + kh * 32 + quad * 8);
        hb[kh] = *(const bf16x8*)(ht + (wave * 16 + col) * 72 + kh * 32 + quad * 8);
    }

    f32x4 acc[4];

    gemm_tile(wl + 0 * (64 * 72), xb, bq, col, quad, acc);
    {
        const size_t tile16 = (size_t)b * KTILES + (n0 >> 4) + wave;
        const float SC = 0.125f * 1.44269504088896f;
        #pragma unroll
        for (int ot = 0; ot < 4; ot++) {
            union { __hip_bfloat16 e[4]; uint2 v; } pk;
            #pragma unroll
            for (int r = 0; r < 4; r++) pk.e[r] = __float2bfloat16(acc[ot][r] * SC);
            *(uint2*)(qS + (tile16 << 10) + (ot >> 1) * 512 +
                      ((ot * 2 + (quad >> 1)) & 3) * 128 + col * 8 +
                      (quad & 1) * 4) = pk.v;
        }
    }

    gemm_tile(wl + 1 * (64 * 72), hb, bk, col, quad, acc);
    {
        const int t_l = (wave >> 1) * 2 + ((col >> 2) & 1);
        const int row = ((wave * 2 + (col >> 3)) & 3) * 4 + (col & 3);
        const size_t tile16 = (size_t)b * KTILES + (n0 >> 4) + t_l;
        #pragma unroll
        for (int ot = 0; ot < 4; ot++) {
            union { __hip_bfloat16 e[4]; uint2 v; } pk;
            #pragma unroll
            for (int r = 0; r < 4; r++) pk.e[r] = __float2bfloat16(acc[ot][r]);
            *(uint2*)(kS + (tile16 << 10) + (ot >> 1) * 512 +
                      ((ot * 2 + (quad >> 1)) & 3) * 128 + row * 8 +
                      (quad & 1) * 4) = pk.v;
        }
    }

    gemm_tile(wl + 2 * (64 * 72), hb, bv, col, quad, acc);
    #pragma unroll
    for (int ot = 0; ot < 4; ot++)
        #pragma unroll
        for (int r = 0; r < 4; r++)
            vl[(ot * 16 + quad * 4 + r) * 72 + wave * 16 + col] =
                __float2bfloat16(acc[ot][r]);
    __syncthreads();
    {
        const size_t vbase = ((size_t)(b * VTILES) + (n0 >> 6)) << 12;
        #pragma unroll
        for (int rep = 0; rep < 2; rep++) {
            const int ch = rep * 256 + t;
            const int cc = ch >> 7, hf = (ch >> 6) & 1;
            const int qd = (ch >> 4) & 3, c2 = ch & 15;
            *(uint4*)(vS + vbase + (size_t)ch * 8) =
                *(const uint4*)(vl + (cc * 16 + c2) * 72 + hf * 32 + qd * 8);
        }
    }
}

// ---------------------------------------------------------------------------
// Flash attention partials: grid = B * 36 * 3 = 216 blocks of 512.
// Block (b, mblk, ns): rows [mblk*128, +128), tokens [ns*1536, +1536).
// 8 waves = (mg 0/1: 64-row half) x (seg 0..3: 384-token quarter).
// Per-wave inner loop identical to R11 (6 tiles of 64 tokens).
// Emits unnormalized O-partials ([b][c][m] layout, f32) + l-partials.
// ---------------------------------------------------------------------------
__global__ __launch_bounds__(512) void attn_kernel(
    const __hip_bfloat16* __restrict__ qS,
    const __hip_bfloat16* __restrict__ kS,
    const __hip_bfloat16* __restrict__ vS,
    float* __restrict__ Pb, float* __restrict__ Lb)
{
    __shared__ float o_lds[2][NSEG][16][OSTR];   // 34.8 KB
    __shared__ float lstat[2][NSEG][64];         // 2 KB

    const int idx  = blockIdx.x;
    const int b    = idx / (M128BLKS * NSPLIT);
    const int rem  = idx % (M128BLKS * NSPLIT);
    const int mblk = rem / NSPLIT;
    const int ns   = rem % NSPLIT;
    const int wave = threadIdx.x >> 6;
    const int lane = threadIdx.x & 63;
    const int col  = lane & 15;
    const int quad = lane >> 4;
    const int mg   = wave >> 2;      // 64-row half
    const int seg  = wave & 3;       // 384-token quarter
    const int m0   = mblk * 128 + mg * 64;

    float* Pns = Pb + (size_t)ns * (B_SZ * C_DIM * N_TOK);
    float* Lns = Lb + (size_t)ns * (B_SZ * N_TOK);

    // loop-invariant Q fragments for this wave's 4 m-subtiles
    const __hip_bfloat16* qp =
        qS + (((size_t)b * KTILES + (m0 >> 4)) << 10) + lane * 8;
    bf16x8 qa[4][2];
    #pragma unroll
    for (int ms = 0; ms < 4; ms++) {
        qa[ms][0] = *(const bf16x8*)(qp + ms * 1024);
        qa[ms][1] = *(const bf16x8*)(qp + ms * 1024 + 512);
    }

    f32x4 accO[4][4];
    #pragma unroll
    for (int ms = 0; ms < 4; ms++)
        #pragma unroll
        for (int cc = 0; cc < 4; cc++)
            accO[ms][cc] = (f32x4){0.f, 0.f, 0.f, 0.f};
    float rsum[4] = {0.f, 0.f, 0.f, 0.f};

    const int nbeg = ns * (NSEG * SEGLEN) + seg * SEGLEN;

    #pragma unroll 1
    for (int t = 0; t < NT; t++) {
        const int n0 = nbeg + t * 64;
        // ---- K/V fragment loads (shared by all 4 m-subtiles) ----
        const __hip_bfloat16* kt =
            kS + (((size_t)b * KTILES + (n0 >> 4)) << 10) + lane * 8;
        bf16x8 ka[8];
        #pragma unroll
        for (int j = 0; j < 4; j++) {
            ka[2 * j]     = *(const bf16x8*)(kt + (j << 10));
            ka[2 * j + 1] = *(const bf16x8*)(kt + (j << 10) + 512);
        }
        const __hip_bfloat16* vt =
            vS + ((((size_t)b * VTILES) + (n0 >> 6)) << 12) + lane * 8;
        bf16x8 va[8];
        #pragma unroll
        for (int cc = 0; cc < 4; cc++) {
            va[2 * cc]     = *(const bf16x8*)(vt + cc * 1024);
            va[2 * cc + 1] = *(const bf16x8*)(vt + cc * 1024 + 512);
        }

        // ---- per m-subtile: S^T -> exp2 -> PV (s regs transient) ----
        #pragma unroll
        for (int ms = 0; ms < 4; ms++) {
            f32x4 s[4];
            #pragma unroll
            for (int j = 0; j < 4; j++) {
                s[j] = __builtin_amdgcn_mfma_f32_16x16x32_bf16(
                           ka[2 * j], qa[ms][0],
                           (f32x4){0.f, 0.f, 0.f, 0.f}, 0, 0, 0);
                s[j] = __builtin_amdgcn_mfma_f32_16x16x32_bf16(
                           ka[2 * j + 1], qa[ms][1], s[j], 0, 0, 0);
            }
            union { __hip_bfloat16 e[8]; bf16x8 v; } p0, p1;
            float ps = 0.f;
            #pragma unroll
            for (int j = 0; j < 2; j++)
                #pragma unroll
                for (int r = 0; r < 4; r++) {
                    float e0 = __builtin_amdgcn_exp2f(s[j][r]);
                    float e1 = __builtin_amdgcn_exp2f(s[2 + j][r]);
                    ps += e0 + e1;
                    p0.e[j * 4 + r] = __float2bfloat16(e0);
                    p1.e[j * 4 + r] = __float2bfloat16(e1);
                }
            rsum[ms] += ps;
            #pragma unroll
            for (int cc = 0; cc < 4; cc++) {
                accO[ms][cc] = __builtin_amdgcn_mfma_f32_16x16x32_bf16(
                                   va[2 * cc], p0.v, accO[ms][cc], 0, 0, 0);
                accO[ms][cc] = __builtin_amdgcn_mfma_f32_16x16x32_bf16(
                                   va[2 * cc + 1], p1.v, accO[ms][cc], 0, 0, 0);
            }
        }
    }

    // ---- finalize per-wave softmax sums ----
    #pragma unroll
    for (int ms = 0; ms < 4; ms++) {
        rsum[ms] += __shfl_xor(rsum[ms], 16);
        rsum[ms] += __shfl_xor(rsum[ms], 32);
    }
    if (quad == 0) {
        #pragma unroll
        for (int ms = 0; ms < 4; ms++) lstat[mg][seg][ms * 16 + col] = rsum[ms];
    }

    // ---- four-phase combine over 4 segments, both m-groups in parallel.
    // Reducer thread t -> (mgR, c, mq): sums rows mq*4..+3 of phase p for
    // channel c; writes P in [b][c][m] layout (f32x4 along m, coalesced).
    #pragma unroll
    for (int p = 0; p < 4; p++) {
        #pragma unroll
        for (int cc = 0; cc < 4; cc++)
            *(f32x4*)(&o_lds[mg][seg][col][cc * 16 + quad * 4]) = accO[p][cc];
        __syncthreads();
        {
            const int t   = threadIdx.x;
            const int mgR = t >> 8;
            const int c   = (t >> 2) & 63;
            const int mq  = t & 3;
            f32x4 os = (f32x4){0.f, 0.f, 0.f, 0.f};
            f32x4 ls = (f32x4){0.f, 0.f, 0.f, 0.f};
            #pragma unroll
            for (int sgm = 0; sgm < NSEG; sgm++)
                #pragma unroll
                for (int j = 0; j < 4; j++) {
                    os[j] += o_lds[mgR][sgm][mq * 4 + j][c];
                    ls[j] += lstat[mgR][sgm][p * 16 + mq * 4 + j];
                }
            const int mabs = mblk * 128 + mgR * 64 + p * 16 + mq * 4;
            *(f32x4*)(Pns + ((size_t)b * C_DIM + c) * N_TOK + mabs) = os;
            if (c == 0)
                *(f32x4*)(Lns + (size_t)b * N_TOK + mabs) = ls;
        }
        __syncthreads();
    }
}

// ---------------------------------------------------------------------------
// Normalize: out = (P0+P1+P2) / (L0+L1+L2). Fully coalesced f32x4.
// grid 576 x 256 covers exactly B*C*N/4 = 147456 vectors.
// ---------------------------------------------------------------------------
__global__ __launch_bounds__(256) void norm_kernel(
    const float* __restrict__ Pb, const float* __restrict__ Lb,
    float* __restrict__ out)
{
    const size_t stride = (size_t)B_SZ * C_DIM * N_TOK;   // 589824
    const size_t f = ((size_t)blockIdx.x * 256 + threadIdx.x) * 4;
    f32x4 o = *(const f32x4*)(Pb + f) +
              *(const f32x4*)(Pb + stride + f) +
              *(const f32x4*)(Pb + 2 * stride + f);
    const int b = (int)(f / ((size_t)C_DIM * N_TOK));
    const int m = (int)(f % N_TOK);
    const size_t lf = (size_t)b * N_TOK + m;
    const size_t lstride = (size_t)B_SZ * N_TOK;          // 9216
    f32x4 l = *(const f32x4*)(Lb + lf) +
              *(const f32x4*)(Lb + lstride + lf) +
              *(const f32x4*)(Lb + 2 * lstride + lf);
    f32x4 r;
    #pragma unroll
    for (int j = 0; j < 4; j++) r[j] = o[j] / l[j];
    *(f32x4*)(out + f) = r;
}

extern "C" void kernel_launch(void* const* d_in, const int* in_sizes, int n_in,
                              void* d_out, int out_size, void* d_ws, size_t ws_size,
                              hipStream_t stream) {
    const float* x  = (const float*)d_in[0];
    const float* h  = (const float*)d_in[1];
    const float* Wq = (const float*)d_in[2];
    const float* bq = (const float*)d_in[3];
    const float* Wk = (const float*)d_in[4];
    const float* bk = (const float*)d_in[5];
    const float* Wv = (const float*)d_in[6];
    const float* bv = (const float*)d_in[7];
    float* out = (float*)d_out;

    const size_t elems = (size_t)B_SZ * N_TOK * C_DIM;   // 589824
    __hip_bfloat16* qS = (__hip_bfloat16*)d_ws;
    __hip_bfloat16* kS = qS + elems;
    __hip_bfloat16* vS = kS + elems;
    float* Pb = (float*)(vS + elems);                    // 3 x 2.36 MB
    float* Lb = Pb + NSPLIT * elems;                     // 3 x 36.9 KB

    proj_kernel<<<B_SZ * NBLK, 256, 0, stream>>>(x, h, Wq, bq, Wk, bk, Wv, bv,
                                                 qS, kS, vS);
    attn_kernel<<<B_SZ * M128BLKS * NSPLIT, 512, 0, stream>>>(qS, kS, vS, Pb, Lb);
    norm_kernel<<<576, 256, 0, stream>>>(Pb, Lb, out);
}